// Round 7
// baseline (134.048 us; speedup 1.0000x reference)
//
#include <hip/hip_runtime.h>
#include <hip/hip_bf16.h>

#define RADIUS_F 1.3f
#define NSAMP 767
#define STEPF 0.01015625f   // RADIUS*2/COARSE/FINE/2
#define BATCH 1024

typedef __attribute__((ext_vector_type(8))) short short8;
typedef __attribute__((ext_vector_type(4))) float floatx4;

static __device__ __forceinline__ unsigned pkbf(float a, float b) {
    union { __hip_bfloat162 h; unsigned u; } cvt;
    cvt.h = __float22bfloat162_rn(make_float2(a, b));
    return cvt.u;
}
static __device__ __forceinline__ unsigned short bf16bits(float a) {
    union { __hip_bfloat16 h; unsigned short u; } cvt;
    cvt.h = __float2bfloat16(a);
    return cvt.u;
}
static __device__ __forceinline__ float frombits(unsigned short u) {
    union { unsigned short u; __hip_bfloat16 h; } cvt;
    cvt.u = u;
    return __bfloat162float(cvt.h);
}

// sum over the 4-lane coset {i, i^4, i^8, i^12} inside each row of 16,
// via DPP row rotates (VALU pipe, no LDS)
static __device__ __forceinline__ float coset4_sum(float p) {
    int q4 = __builtin_amdgcn_update_dpp(0, __float_as_int(p), 0x124, 0xf, 0xf, true); // row_ror:4
    p = p + __int_as_float(q4);
    int q8 = __builtin_amdgcn_update_dpp(0, __float_as_int(p), 0x128, 0xf, 0xf, true); // row_ror:8
    return p + __int_as_float(q8);
}

// ============ kernel 1: per-sample alpha + rgb (3 blocks per ray) ============
__launch_bounds__(256, 4)
__global__ void plen_samples(const float* __restrict__ rays_o,
                             const float* __restrict__ rays_d,
                             const float* __restrict__ grid,
                             const float* __restrict__ atoms,
                             float* __restrict__ out_alpha,
                             uint2* __restrict__ pack)
{
    // LDS: 4096 (B'') + 8320 (Wf) + 1024 (clin) + 2048 (pack) = 15488 B
    __shared__ __align__(16) __hip_bfloat16 BpL[32 * 64];  // Bp[col][a], col = 4f+c
    __shared__ float Wf[4][8][65];                          // per-wave W SoA, stride 65
    __shared__ int clinT[4][64];
    __shared__ __align__(16) uint2 packT[4][64];            // {r|g<<16, b|al<<16} bf16 bits

    const int tid  = threadIdx.x;
    const int bid  = blockIdx.x;
    const int ray  = bid / 3;
    const int seg  = bid - ray * 3;
    const int lane = tid & 63;
    const int w    = tid >> 6;
    const int job  = seg * 4 + w;        // 0..11
    const int sbase = job * 64;
    const int m    = lane & 15;
    const int quad = lane >> 4;

    // ---- per-ray constants ----
    const float ox = rays_o[ray * 3 + 0], oy = rays_o[ray * 3 + 1], oz = rays_o[ray * 3 + 2];
    const float dx = rays_d[ray * 3 + 0], dy = rays_d[ray * 3 + 1], dz = rays_d[ray * 3 + 2];

    float start;
    {
        float a0 = (RADIUS_F - ox) / dx, b0 = (-RADIUS_F - ox) / dx;
        float a1 = (RADIUS_F - oy) / dy, b1 = (-RADIUS_F - oy) / dy;
        float a2 = (RADIUS_F - oz) / dz, b2 = (-RADIUS_F - oz) / dz;
        start = fmaxf(fminf(a0, b0), fmaxf(fminf(a1, b1), fminf(a2, b2)));
    }
    const float dnorm = sqrtf(dx * dx + dy * dy + dz * dz);
    const float dist = STEPF * dnorm;

    float shm[9];
    {
        float inv = 1.0f / dnorm;
        float nx = dx * inv, ny = dy * inv, nz = dz * inv;
        shm[0] = 0.28209479177387814f;
        shm[1] = -0.4886025119029199f * ny;
        shm[2] = 0.4886025119029199f * nz;
        shm[3] = -0.4886025119029199f * nx;
        shm[4] = 1.0925484305920792f * nx * ny;
        shm[5] = -1.0925484305920792f * ny * nz;
        shm[6] = 0.31539156525252005f * (2.f * nz * nz - nx * nx - ny * ny);
        shm[7] = -1.0925484305920792f * nx * nz;
        shm[8] = 0.5462742152960396f * (nx * nx - ny * ny);
    }

    // ---- per-lane geometry for this wave's 64 samples (computed ONCE) ----
    {
        const int s = sbase + lane;
        float tr = start + (float)s * STEPF;
        float px = ox + tr * dx, py = oy + tr * dy, pz = oz + tr * dz;
        int mask = (px > -RADIUS_F) & (px < RADIUS_F) &
                   (py > -RADIUS_F) & (py < RADIUS_F) &
                   (pz > -RADIUS_F) & (pz < RADIUS_F);
        float maskf = mask ? 1.f : 0.f;
        const float sc = 1.0f / (2.0f * RADIUS_F);
        float qx = fminf(fmaxf((px + RADIUS_F) * sc, 0.f), 1.0f - 1e-6f);
        float qy = fminf(fmaxf((py + RADIUS_F) * sc, 0.f), 1.0f - 1e-6f);
        float qz = fminf(fmaxf((pz + RADIUS_F) * sc, 0.f), 1.0f - 1e-6f);
        float pcx = qx * 64.f, pcy = qy * 64.f, pcz = qz * 64.f;
        float cx = fminf(floorf(pcx), 63.f);
        float cy = fminf(floorf(pcy), 63.f);
        float cz = fminf(floorf(pcz), 63.f);
        float lx = pcx - cx, ly = pcy - cy, lz = pcz - cz;
        int clin = (((int)cx * 64) + (int)cy) * 64 + (int)cz;
        float xw0, xw1, yw0, yw1, zw0, zw1;
        {
            float u = lx * 2.f - 0.5f, fF = floorf(u), t = u - fF;
            xw0 = (fF < 0.f) ? 1.f : ((fF > 0.f) ? 0.f : 1.f - t);
            xw1 = (fF < 0.f) ? 0.f : ((fF > 0.f) ? 1.f : t);
        }
        {
            float u = ly * 2.f - 0.5f, fF = floorf(u), t = u - fF;
            yw0 = (fF < 0.f) ? 1.f : ((fF > 0.f) ? 0.f : 1.f - t);
            yw1 = (fF < 0.f) ? 0.f : ((fF > 0.f) ? 1.f : t);
        }
        {
            float u = lz * 2.f - 0.5f, fF = floorf(u), t = u - fF;
            zw0 = (fF < 0.f) ? 1.f : ((fF > 0.f) ? 0.f : 1.f - t);
            zw1 = (fF < 0.f) ? 0.f : ((fF > 0.f) ? 1.f : t);
        }
        xw0 *= maskf; xw1 *= maskf;          // fold mask: W=0 => sigma=0, rgb pre-act=0
        Wf[w][0][lane] = xw0 * yw0 * zw0;
        Wf[w][1][lane] = xw0 * yw0 * zw1;
        Wf[w][2][lane] = xw0 * yw1 * zw0;
        Wf[w][3][lane] = xw0 * yw1 * zw1;
        Wf[w][4][lane] = xw1 * yw0 * zw0;
        Wf[w][5][lane] = xw1 * yw0 * zw1;
        Wf[w][6][lane] = xw1 * yw1 * zw0;
        Wf[w][7][lane] = xw1 * yw1 * zw1;
        clinT[w][lane] = clin;
    }

    // ---- tile-0 coeff gather issues now; latency hides under B'' build ----
    const float4* g4 = (const float4*)grid;
    float4 cv0, cv1, cv2, cv3;
    {
        int clinC = clinT[w][m];
        const float4* gp = g4 + (clinC << 4) + (quad << 2);
        cv0 = gp[0]; cv1 = gp[1]; cv2 = gp[2]; cv3 = gp[3];
    }

    // ---- build B''[a][col] (SH-contracted atoms), Bp[col][a], col = 4f+c ----
    for (int idx = tid; idx < 2048; idx += 256) {
        int col = idx >> 6, a = idx & 63;     // col uniform per wave per sweep
        int f = col >> 2, c = col & 3;
        const float* base = atoms + (f * 64 + a) * 28;
        float sv;
        if (c == 3) sv = base[27];
        else {
            sv = 0.f;
            #pragma unroll
            for (int i = 0; i < 9; ++i) sv = fmaf(base[c * 9 + i], shm[i], sv);
        }
        BpL[col * 64 + a] = __float2bfloat16(sv);
    }
    __syncthreads();

    // ---- B-fragments (tile-invariant) ----
    short8 bq00, bq01, bq10, bq11;
    {
        const short* bs = (const short*)BpL;
        const short* p0 = bs + m * 64 + (quad << 4);
        bq00 = *(const short8*)(p0);
        bq01 = *(const short8*)(p0 + 8);
        const short* p1 = bs + (16 + m) * 64 + (quad << 4);
        bq10 = *(const short8*)(p1);
        bq11 = *(const short8*)(p1 + 8);
    }

    unsigned short* ps = (unsigned short*)packT;
    const int f0 = m >> 2;

    for (int t = 0; t < 4; ++t) {
        // A-frags: raw coeff, bf16 (step ks uses a = 16*quad + ks)
        union { unsigned u[4]; short8 s; } a0, a1;
        a0.u[0] = pkbf(cv0.x, cv0.y); a0.u[1] = pkbf(cv0.z, cv0.w);
        a0.u[2] = pkbf(cv1.x, cv1.y); a0.u[3] = pkbf(cv1.z, cv1.w);
        a1.u[0] = pkbf(cv2.x, cv2.y); a1.u[1] = pkbf(cv2.z, cv2.w);
        a1.u[2] = pkbf(cv3.x, cv3.y); a1.u[3] = pkbf(cv3.z, cv3.w);

        // prefetch next tile's coeff gather
        if (t < 3) {
            int clinC = clinT[w][((t + 1) << 4) + m];
            const float4* gp = g4 + (clinC << 4) + (quad << 2);
            cv0 = gp[0]; cv1 = gp[1]; cv2 = gp[2]; cv3 = gp[3];
        }

        // stage 1: proj = Coeff(16x64) x B''(64x32)
        floatx4 acc0 = {0.f, 0.f, 0.f, 0.f};
        floatx4 acc1 = {0.f, 0.f, 0.f, 0.f};
        acc0 = __builtin_amdgcn_mfma_f32_16x16x32_bf16(a0.s, bq00, acc0, 0, 0, 0);
        acc0 = __builtin_amdgcn_mfma_f32_16x16x32_bf16(a1.s, bq01, acc0, 0, 0, 0);
        acc1 = __builtin_amdgcn_mfma_f32_16x16x32_bf16(a0.s, bq10, acc1, 0, 0, 0);
        acc1 = __builtin_amdgcn_mfma_f32_16x16x32_bf16(a1.s, bq11, acc1, 0, 0, 0);

        // stage 2: out[s][c] = sum_f W[s][f] * proj[s][4f+c]
        #pragma unroll
        for (int r = 0; r < 4; ++r) {
            int sl = (t << 4) + (quad << 2) + r;      // local sample 0..63
            float wA = Wf[w][f0][sl];
            float wB = Wf[w][4 + f0][sl];
            float p = wA * acc0[r] + wB * acc1[r];
            p = coset4_sum(p);                        // reduce over f
            float val;
            if (m == 3) {                             // sigma -> alpha
                val = 1.f - __expf(-fmaxf(p, 0.f) * dist);
                int s = sbase + sl;
                if (s < NSAMP) out_alpha[ray * NSAMP + s] = val;  // exact fp32
            } else {
                val = 1.f / (1.f + __expf(-p));       // sigmoid (rgb lanes m<3)
            }
            if (m < 4) ps[(((w << 6) + sl) << 2) + m] = bf16bits(val);
        }
    }

    // same-wave LDS program order; store packed samples coalesced
    uint2 pk = packT[w][lane];
    pack[ray * 768 + sbase + lane] = pk;
}

// ============ kernel 2: transmittance scan + composite (1 wave per ray) ============
__launch_bounds__(256, 2)
__global__ void plen_composite(const float* __restrict__ rays_o,
                               const float* __restrict__ rays_d,
                               const uint2* __restrict__ pack,
                               float* __restrict__ out)
{
    const int tid  = threadIdx.x;
    const int lane = tid & 63;
    const int w    = tid >> 6;
    const int ray  = blockIdx.x * 4 + w;

    const float ox = rays_o[ray * 3 + 0], oy = rays_o[ray * 3 + 1], oz = rays_o[ray * 3 + 2];
    const float dx = rays_d[ray * 3 + 0], dy = rays_d[ray * 3 + 1], dz = rays_d[ray * 3 + 2];
    float start;
    {
        float a0 = (RADIUS_F - ox) / dx, b0 = (-RADIUS_F - ox) / dx;
        float a1 = (RADIUS_F - oy) / dy, b1 = (-RADIUS_F - oy) / dy;
        float a2 = (RADIUS_F - oz) / dz, b2 = (-RADIUS_F - oz) / dz;
        start = fmaxf(fminf(a0, b0), fmaxf(fminf(a1, b1), fminf(a2, b2)));
    }

    float* out_rgb   = out;
    float* out_depth = out + BATCH * 3 + BATCH * NSAMP;

    const int sA = lane * 12;
    const int sB = min(sA + 12, NSAMP);
    const uint2* pr = pack + ray * 768 + sA;

    uint2 e[12];
    #pragma unroll
    for (int i = 0; i < 12; ++i) e[i] = pr[i];

    float prod = 1.f;
    for (int s = sA; s < sB; ++s) {
        float a = frombits((unsigned short)(e[s - sA].y >> 16));
        prod *= (1.f - a + 1e-10f);
    }

    float incl = prod;
    #pragma unroll
    for (int off = 1; off < 64; off <<= 1) {
        float v = __shfl_up(incl, off, 64);
        if (lane >= off) incl *= v;
    }
    float excl = __shfl_up(incl, 1, 64);
    if (lane == 0) excl = 1.f;

    float trans = excl;
    float c0 = 0.f, c1 = 0.f, c2 = 0.f, acc = 0.f, dep = 0.f;
    for (int s = sA; s < sB; ++s) {
        uint2 ev = e[s - sA];
        float a  = frombits((unsigned short)(ev.y >> 16));
        float wgt = a * trans;
        c0 += wgt * frombits((unsigned short)(ev.x & 0xffff));
        c1 += wgt * frombits((unsigned short)(ev.x >> 16));
        c2 += wgt * frombits((unsigned short)(ev.y & 0xffff));
        acc += wgt;
        dep += wgt * (start + (float)s * STEPF);
        trans *= (1.f - a + 1e-10f);
    }
    #pragma unroll
    for (int off = 1; off < 64; off <<= 1) {
        c0  += __shfl_xor(c0, off, 64);
        c1  += __shfl_xor(c1, off, 64);
        c2  += __shfl_xor(c2, off, 64);
        acc += __shfl_xor(acc, off, 64);
        dep += __shfl_xor(dep, off, 64);
    }
    if (lane == 0) {
        float bg = 1.f - acc;
        out_rgb[ray * 3 + 0] = c0 + bg;
        out_rgb[ray * 3 + 1] = c1 + bg;
        out_rgb[ray * 3 + 2] = c2 + bg;
        out_depth[ray] = dep;
    }
}

extern "C" void kernel_launch(void* const* d_in, const int* in_sizes, int n_in,
                              void* d_out, int out_size, void* d_ws, size_t ws_size,
                              hipStream_t stream) {
    const float* rays_o = (const float*)d_in[0];
    const float* rays_d = (const float*)d_in[1];
    const float* grid   = (const float*)d_in[2];
    const float* atoms  = (const float*)d_in[3];
    float* out  = (float*)d_out;
    uint2* pack = (uint2*)d_ws;   // 1024*768*8 B = 6.3 MB of workspace

    hipLaunchKernelGGL(plen_samples, dim3(BATCH * 3), dim3(256), 0, stream,
                       rays_o, rays_d, grid, atoms, out + BATCH * 3, pack);
    hipLaunchKernelGGL(plen_composite, dim3(BATCH / 4), dim3(256), 0, stream,
                       rays_o, rays_d, pack, out);
}

// Round 8
// 120.735 us; speedup vs baseline: 1.1103x; 1.1103x over previous
//
#include <hip/hip_runtime.h>
#include <hip/hip_bf16.h>

#define RADIUS_F 1.3f
#define NSAMP 767
#define STEPF 0.01015625f   // RADIUS*2/COARSE/FINE/2
#define BATCH 1024

typedef __attribute__((ext_vector_type(8))) short short8;
typedef __attribute__((ext_vector_type(4))) float floatx4;

static __device__ __forceinline__ unsigned pkbf(float a, float b) {
    union { __hip_bfloat162 h; unsigned u; } cvt;
    cvt.h = __float22bfloat162_rn(make_float2(a, b));
    return cvt.u;
}

// sum over the 4-lane coset {i, i^4, i^8, i^12} inside each row of 16,
// via DPP row rotates (VALU pipe, no LDS)
static __device__ __forceinline__ float coset4_sum(float p) {
    int q4 = __builtin_amdgcn_update_dpp(0, __float_as_int(p), 0x124, 0xf, 0xf, true); // row_ror:4
    p = p + __int_as_float(q4);
    int q8 = __builtin_amdgcn_update_dpp(0, __float_as_int(p), 0x128, 0xf, 0xf, true); // row_ror:8
    return p + __int_as_float(q8);
}

// launch_bounds (512,8): 8 waves/EU -> 4 blocks/CU -> 32 waves/CU (VGPR target <=64)
__launch_bounds__(512, 8)
__global__ void plenoxels_fwd(const float* __restrict__ rays_o,
                              const float* __restrict__ rays_d,
                              const float* __restrict__ grid,
                              const float* __restrict__ atoms,
                              float* __restrict__ out)
{
    // LDS: 4096 (B'') + 27648 (Wf stride-9) + 1536 (alpha) + 4608 (rgb) = 37888 B
    __shared__ __align__(16) __hip_bfloat16 BpL[32 * 64];   // Bp[col][a], col = 4f+c
    __shared__ float Wf[768 * 9];                           // W[s][f], stride 9 (conflict-free)
    __shared__ __align__(16) __hip_bfloat16 alphaL[768];
    __shared__ __align__(16) __hip_bfloat16 rgbL[768 * 3];

    const int tid  = threadIdx.x;
    const int ray  = blockIdx.x;
    const int lane = tid & 63;
    const int w    = tid >> 6;        // 8 waves; wave owns samples [96w, 96w+96)
    const int m    = lane & 15;
    const int quad = lane >> 4;

    // ---- per-ray constants ----
    const float ox = rays_o[ray * 3 + 0], oy = rays_o[ray * 3 + 1], oz = rays_o[ray * 3 + 2];
    const float dx = rays_d[ray * 3 + 0], dy = rays_d[ray * 3 + 1], dz = rays_d[ray * 3 + 2];

    float start;
    {
        float a0 = (RADIUS_F - ox) / dx, b0 = (-RADIUS_F - ox) / dx;
        float a1 = (RADIUS_F - oy) / dy, b1 = (-RADIUS_F - oy) / dy;
        float a2 = (RADIUS_F - oz) / dz, b2 = (-RADIUS_F - oz) / dz;
        start = fmaxf(fminf(a0, b0), fmaxf(fminf(a1, b1), fminf(a2, b2)));
    }
    const float dnorm = sqrtf(dx * dx + dy * dy + dz * dz);
    const float dist = STEPF * dnorm;

    // geometry for one sample: writes W row to LDS, returns clin
    auto geom = [&](int s) -> int {
        float tr = start + (float)s * STEPF;
        float px = ox + tr * dx, py = oy + tr * dy, pz = oz + tr * dz;
        int mask = (px > -RADIUS_F) & (px < RADIUS_F) &
                   (py > -RADIUS_F) & (py < RADIUS_F) &
                   (pz > -RADIUS_F) & (pz < RADIUS_F) & (s < NSAMP);
        float maskf = mask ? 1.f : 0.f;
        const float sc = 1.0f / (2.0f * RADIUS_F);
        float qx = fminf(fmaxf((px + RADIUS_F) * sc, 0.f), 1.0f - 1e-6f);
        float qy = fminf(fmaxf((py + RADIUS_F) * sc, 0.f), 1.0f - 1e-6f);
        float qz = fminf(fmaxf((pz + RADIUS_F) * sc, 0.f), 1.0f - 1e-6f);
        float pcx = qx * 64.f, pcy = qy * 64.f, pcz = qz * 64.f;
        float cx = fminf(floorf(pcx), 63.f);
        float cy = fminf(floorf(pcy), 63.f);
        float cz = fminf(floorf(pcz), 63.f);
        float lx = pcx - cx, ly = pcy - cy, lz = pcz - cz;
        int clin = (((int)cx * 64) + (int)cy) * 64 + (int)cz;
        float xw0, xw1, yw0, yw1, zw0, zw1;
        {
            float u = lx * 2.f - 0.5f, fF = floorf(u), t = u - fF;
            xw0 = (fF < 0.f) ? 1.f : ((fF > 0.f) ? 0.f : 1.f - t);
            xw1 = (fF < 0.f) ? 0.f : ((fF > 0.f) ? 1.f : t);
        }
        {
            float u = ly * 2.f - 0.5f, fF = floorf(u), t = u - fF;
            yw0 = (fF < 0.f) ? 1.f : ((fF > 0.f) ? 0.f : 1.f - t);
            yw1 = (fF < 0.f) ? 0.f : ((fF > 0.f) ? 1.f : t);
        }
        {
            float u = lz * 2.f - 0.5f, fF = floorf(u), t = u - fF;
            zw0 = (fF < 0.f) ? 1.f : ((fF > 0.f) ? 0.f : 1.f - t);
            zw1 = (fF < 0.f) ? 0.f : ((fF > 0.f) ? 1.f : t);
        }
        xw0 *= maskf; xw1 *= maskf;          // fold mask: W=0 => sigma=0, rgb pre-act=0
        float* wr = &Wf[s * 9];
        wr[0] = xw0 * yw0 * zw0;
        wr[1] = xw0 * yw0 * zw1;
        wr[2] = xw0 * yw1 * zw0;
        wr[3] = xw0 * yw1 * zw1;
        wr[4] = xw1 * yw0 * zw0;
        wr[5] = xw1 * yw0 * zw1;
        wr[6] = xw1 * yw1 * zw0;
        wr[7] = xw1 * yw1 * zw1;
        return clin;
    };

    // ---- wave-local geometry: pass A (64 samples) + pass B (32 samples) ----
    int clinA = geom(w * 96 + lane);
    int clinB = 0;
    if (lane < 32) clinB = geom(w * 96 + 64 + lane);

    // ---- tile-0 coeff gather issues now; latency hides under B'' build ----
    const float4* g4 = (const float4*)grid;
    float4 cv0, cv1, cv2, cv3;
    {
        int clinC = __shfl(clinA, m, 64);
        const float4* gp = g4 + (clinC << 4) + (quad << 2);
        cv0 = gp[0]; cv1 = gp[1]; cv2 = gp[2]; cv3 = gp[3];
    }

    // ---- build B''[a][col] (SH-contracted atoms), Bp[col][a], col = 4f+c ----
    {
        float shm[9];
        float inv = 1.0f / dnorm;
        float nx = dx * inv, ny = dy * inv, nz = dz * inv;
        shm[0] = 0.28209479177387814f;
        shm[1] = -0.4886025119029199f * ny;
        shm[2] = 0.4886025119029199f * nz;
        shm[3] = -0.4886025119029199f * nx;
        shm[4] = 1.0925484305920792f * nx * ny;
        shm[5] = -1.0925484305920792f * ny * nz;
        shm[6] = 0.31539156525252005f * (2.f * nz * nz - nx * nx - ny * ny);
        shm[7] = -1.0925484305920792f * nx * nz;
        shm[8] = 0.5462742152960396f * (nx * nx - ny * ny);
        for (int idx = tid; idx < 2048; idx += 512) {
            int col = idx >> 6, a = idx & 63;     // col uniform per wave per sweep
            int f = col >> 2, c = col & 3;
            const float* base = atoms + (f * 64 + a) * 28;
            float sv;
            if (c == 3) sv = base[27];
            else {
                sv = 0.f;
                #pragma unroll
                for (int i = 0; i < 9; ++i) sv = fmaf(base[c * 9 + i], shm[i], sv);
            }
            BpL[col * 64 + a] = __float2bfloat16(sv);
        }
    }
    __syncthreads();

    // ---- B-fragments (tile-invariant) ----
    short8 bq00, bq01, bq10, bq11;
    {
        const short* bs = (const short*)BpL;
        const short* p0 = bs + m * 64 + (quad << 4);
        bq00 = *(const short8*)(p0);
        bq01 = *(const short8*)(p0 + 8);
        const short* p1 = bs + (16 + m) * 64 + (quad << 4);
        bq10 = *(const short8*)(p1);
        bq11 = *(const short8*)(p1 + 8);
    }

    float* out_rgb   = out;
    float* out_alpha = out + BATCH * 3;
    float* out_depth = out + BATCH * 3 + BATCH * NSAMP;
    const int f0 = m >> 2;

    #pragma unroll
    for (int t = 0; t < 6; ++t) {
        // A-frags: raw coeff, bf16 (step ks uses a = 16*quad + ks)
        union { unsigned u[4]; short8 s; } a0, a1;
        a0.u[0] = pkbf(cv0.x, cv0.y); a0.u[1] = pkbf(cv0.z, cv0.w);
        a0.u[2] = pkbf(cv1.x, cv1.y); a0.u[3] = pkbf(cv1.z, cv1.w);
        a1.u[0] = pkbf(cv2.x, cv2.y); a1.u[1] = pkbf(cv2.z, cv2.w);
        a1.u[2] = pkbf(cv3.x, cv3.y); a1.u[3] = pkbf(cv3.z, cv3.w);

        // prefetch next tile's coeff gather (clin via shuffle, wave-local)
        if (t < 5) {
            int tn = t + 1;
            int clinC = (tn < 4) ? __shfl(clinA, (tn << 4) + m, 64)
                                 : __shfl(clinB, ((tn - 4) << 4) + m, 64);
            const float4* gp = g4 + (clinC << 4) + (quad << 2);
            cv0 = gp[0]; cv1 = gp[1]; cv2 = gp[2]; cv3 = gp[3];
        }

        // stage 1: proj = Coeff(16x64) x B''(64x32)
        floatx4 acc0 = {0.f, 0.f, 0.f, 0.f};
        floatx4 acc1 = {0.f, 0.f, 0.f, 0.f};
        acc0 = __builtin_amdgcn_mfma_f32_16x16x32_bf16(a0.s, bq00, acc0, 0, 0, 0);
        acc0 = __builtin_amdgcn_mfma_f32_16x16x32_bf16(a1.s, bq01, acc0, 0, 0, 0);
        acc1 = __builtin_amdgcn_mfma_f32_16x16x32_bf16(a0.s, bq10, acc1, 0, 0, 0);
        acc1 = __builtin_amdgcn_mfma_f32_16x16x32_bf16(a1.s, bq11, acc1, 0, 0, 0);

        // stage 2: out[s][c] = sum_f W[s][f] * proj[s][4f+c]
        #pragma unroll
        for (int r = 0; r < 4; ++r) {
            int s = w * 96 + (t << 4) + (quad << 2) + r;
            const float* wr = &Wf[s * 9];
            float p = wr[f0] * acc0[r] + wr[4 + f0] * acc1[r];
            p = coset4_sum(p);                 // reduce over f
            if (s < NSAMP) {
                if (m == 3) {                  // sigma -> alpha
                    float al = 1.f - __expf(-fmaxf(p, 0.f) * dist);
                    out_alpha[ray * NSAMP + s] = al;   // exact fp32 output
                    alphaL[s] = __float2bfloat16(al);
                } else if (m < 3) {            // rgb channels
                    rgbL[s * 3 + m] = __float2bfloat16(1.f / (1.f + __expf(-p)));
                }
            }
        }
    }

    __syncthreads();

    // ---- phase 2: transmittance scan + composite (wave 0 only) ----
    if (tid < 64) {
        int sA = tid * 12;
        int sB = min(sA + 12, NSAMP);
        float prod = 1.f;
        for (int s = sA; s < sB; ++s)
            prod *= (1.f - __bfloat162float(alphaL[s]) + 1e-10f);

        float incl = prod;
        #pragma unroll
        for (int off = 1; off < 64; off <<= 1) {
            float v = __shfl_up(incl, off, 64);
            if (tid >= off) incl *= v;
        }
        float excl = __shfl_up(incl, 1, 64);
        if (tid == 0) excl = 1.f;

        float trans = excl;
        float c0 = 0.f, c1 = 0.f, c2 = 0.f, acc = 0.f, dep = 0.f;
        for (int s = sA; s < sB; ++s) {
            float a = __bfloat162float(alphaL[s]);
            float wgt = a * trans;
            c0 += wgt * __bfloat162float(rgbL[s * 3 + 0]);
            c1 += wgt * __bfloat162float(rgbL[s * 3 + 1]);
            c2 += wgt * __bfloat162float(rgbL[s * 3 + 2]);
            acc += wgt;
            dep += wgt * (start + (float)s * STEPF);
            trans *= (1.f - a + 1e-10f);
        }
        #pragma unroll
        for (int off = 1; off < 64; off <<= 1) {
            c0  += __shfl_xor(c0, off, 64);
            c1  += __shfl_xor(c1, off, 64);
            c2  += __shfl_xor(c2, off, 64);
            acc += __shfl_xor(acc, off, 64);
            dep += __shfl_xor(dep, off, 64);
        }
        if (tid == 0) {
            float bg = 1.f - acc;
            out_rgb[ray * 3 + 0] = c0 + bg;
            out_rgb[ray * 3 + 1] = c1 + bg;
            out_rgb[ray * 3 + 2] = c2 + bg;
            out_depth[ray] = dep;
        }
    }
}

extern "C" void kernel_launch(void* const* d_in, const int* in_sizes, int n_in,
                              void* d_out, int out_size, void* d_ws, size_t ws_size,
                              hipStream_t stream) {
    const float* rays_o = (const float*)d_in[0];
    const float* rays_d = (const float*)d_in[1];
    const float* grid   = (const float*)d_in[2];
    const float* atoms  = (const float*)d_in[3];
    float* out = (float*)d_out;
    hipLaunchKernelGGL(plenoxels_fwd, dim3(BATCH), dim3(512), 0, stream,
                       rays_o, rays_d, grid, atoms, out);
}